// Round 1
// baseline (2397.754 us; speedup 1.0000x reference)
//
#include <hip/hip_runtime.h>

#define NN 100000
#define NE 1600000
#define D 32

// ---------------- CSR build (dst -> edge list), once per launch ----------------

__global__ void k_deg(const int* __restrict__ dst, int* __restrict__ cnt) {
  int i = blockIdx.x * blockDim.x + threadIdx.x;
  int stride = gridDim.x * blockDim.x;
  for (int e = i; e < NE; e += stride) atomicAdd(&cnt[dst[e]], 1);
}

__global__ void k_invdeg(const int* __restrict__ cnt, float* __restrict__ inv) {
  int v = blockIdx.x * blockDim.x + threadIdx.x;
  if (v < NN) inv[v] = 1.0f / (float)max(cnt[v], 1);
}

__global__ __launch_bounds__(1024) void k_scanA(const int* __restrict__ cnt,
                                                int* __restrict__ rowptr,
                                                int* __restrict__ partial) {
  __shared__ int lds[1024];
  int t = threadIdx.x;
  int i = blockIdx.x * 1024 + t;
  int v = (i < NN) ? cnt[i] : 0;
  lds[t] = v;
  __syncthreads();
  for (int off = 1; off < 1024; off <<= 1) {
    int add = (t >= off) ? lds[t - off] : 0;
    __syncthreads();
    lds[t] += add;
    __syncthreads();
  }
  if (i < NN) rowptr[i] = lds[t] - v;  // exclusive within block
  if (t == 1023) partial[blockIdx.x] = lds[1023];
}

__global__ void k_scanB(int* __restrict__ partial, int nb) {
  // single thread serial scan over ~98 entries
  int acc = 0;
  for (int b = 0; b < nb; b++) { int t = partial[b]; partial[b] = acc; acc += t; }
  partial[nb] = acc;
}

__global__ __launch_bounds__(1024) void k_scanC(int* __restrict__ rowptr,
                                                const int* __restrict__ partial) {
  int t = threadIdx.x;
  int i = blockIdx.x * 1024 + t;
  if (i < NN) rowptr[i] += partial[blockIdx.x];
  if (i == 0) rowptr[NN] = NE;
}

__global__ void k_fill(const int* __restrict__ dst, const int* __restrict__ rowptr,
                       int* __restrict__ fill, int* __restrict__ eidx) {
  int i = blockIdx.x * blockDim.x + threadIdx.x;
  int stride = gridDim.x * blockDim.x;
  for (int e = i; e < NE; e += stride) {
    int d = dst[e];
    int s = atomicAdd(&fill[d], 1);
    eidx[rowptr[d] + s] = e;
  }
}

// ---------------- helpers ----------------

template <int K4>
__device__ inline float dot_lds(const float* __restrict__ lv, const float* __restrict__ Wc) {
  float acc = 0.f;
  const float4* v4 = (const float4*)lv;
#pragma unroll
  for (int kk = 0; kk < K4; kk++) {
    float4 h = v4[kk];
    acc = fmaf(h.x, Wc[4 * kk + 0], acc);
    acc = fmaf(h.y, Wc[4 * kk + 1], acc);
    acc = fmaf(h.z, Wc[4 * kk + 2], acc);
    acc = fmaf(h.w, Wc[4 * kk + 3], acc);
  }
  return acc;
}

// ---------------- encoders ----------------
// scheme: 32 lanes per item; lane j owns channel j and holds weight column j.

__global__ __launch_bounds__(256) void k_node_enc(
    const float* __restrict__ x,
    const float* __restrict__ ws, const float* __restrict__ bs,
    const float* __restrict__ wh, const float* __restrict__ bh,
    const float* __restrict__ we, const float* __restrict__ be,
    float* __restrict__ h_out) {
  __shared__ float lds[8][D];
  int t = threadIdx.x, j = t & 31, g = t >> 5;
  float Ws = ws[j], Bs = bs[j], Bh = bh[j], Be = be[j];
  float Wh[D], We_[D];
#pragma unroll
  for (int k = 0; k < D; k++) { Wh[k] = wh[k * D + j]; We_[k] = we[k * D + j]; }
  for (int v = blockIdx.x * 8 + g; v < NN; v += gridDim.x * 8) {
    float xv = x[v];
    float h = fmaxf(fmaf(xv, Ws, Bs), 0.f);
#pragma unroll
    for (int L = 0; L < 2; L++) {  // shared hidden layer applied twice
      lds[g][j] = h;
      h = fmaxf(dot_lds<8>(lds[g], Wh) + Bh, 0.f);
    }
    lds[g][j] = h;
    h = fmaxf(dot_lds<8>(lds[g], We_) + Be, 0.f);
    h_out[(size_t)v * D + j] = h;
  }
}

__global__ __launch_bounds__(256) void k_edge_enc(
    const float* __restrict__ ea,
    const float* __restrict__ ws, const float* __restrict__ bs,
    const float* __restrict__ wh, const float* __restrict__ bh,
    const float* __restrict__ we, const float* __restrict__ be,
    float* __restrict__ h_out) {
  __shared__ float lds[8][D];
  int t = threadIdx.x, j = t & 31, g = t >> 5;
  float Ws0 = ws[0 * D + j], Ws1 = ws[1 * D + j], Ws2 = ws[2 * D + j];
  float Bs = bs[j], Bh = bh[j], Be = be[j];
  float Wh[D], We_[D];
#pragma unroll
  for (int k = 0; k < D; k++) { Wh[k] = wh[k * D + j]; We_[k] = we[k * D + j]; }
  for (int e = blockIdx.x * 8 + g; e < NE; e += gridDim.x * 8) {
    float a0 = ea[(size_t)e * 3 + 0], a1 = ea[(size_t)e * 3 + 1], a2 = ea[(size_t)e * 3 + 2];
    float h = fmaf(a0, Ws0, fmaf(a1, Ws1, fmaf(a2, Ws2, Bs)));
    h = fmaxf(h, 0.f);
#pragma unroll
    for (int L = 0; L < 2; L++) {
      lds[g][j] = h;
      h = fmaxf(dot_lds<8>(lds[g], Wh) + Bh, 0.f);
    }
    lds[g][j] = h;
    h = fmaxf(dot_lds<8>(lds[g], We_) + Be, 0.f);
    h_out[(size_t)e * D + j] = h;
  }
}

// ---------------- node proc: fused message + CSR gather-mean ----------------
// h_node_out[v] = (1/deg) * sum_{e: dst[e]==v} relu([h_node_in[src[e]] | h_edge[e]] @ W)

__global__ __launch_bounds__(256) void k_node_proc(
    const float* __restrict__ h_node_in, const float* __restrict__ h_edge,
    const int* __restrict__ srcs,
    const int* __restrict__ rowptr, const int* __restrict__ eidx,
    const float* __restrict__ inv_deg,
    const float* __restrict__ W,  // [64][32]
    float* __restrict__ h_node_out) {
  __shared__ float vec[2][8][2 * D];
  int t = threadIdx.x, j = t & 31, g = t >> 5;
  float Wc[2 * D];
#pragma unroll
  for (int k = 0; k < 2 * D; k++) Wc[k] = W[k * D + j];
  for (int v = blockIdx.x * 8 + g; v < NN; v += gridDim.x * 8) {
    float acc = 0.f;
    int beg = rowptr[v], end = rowptr[v + 1];
    int it = 0;
    for (int p = beg; p < end; ++p, ++it) {
      int e = eidx[p];
      int s = srcs[e];
      float* vv = vec[it & 1][g];
      vv[j] = h_node_in[(size_t)s * D + j];
      vv[D + j] = h_edge[(size_t)e * D + j];
      float m = dot_lds<16>(vv, Wc);
      acc += fmaxf(m, 0.f);
    }
    h_node_out[(size_t)v * D + j] = acc * inv_deg[v];
  }
}

// ---------------- edge update: h_edge = relu([h_e | h_src | h_dst] @ W + b), in place ----------------

__global__ __launch_bounds__(256) void k_edge_upd(
    float* __restrict__ h_edge, const float* __restrict__ h_node,
    const int* __restrict__ srcs, const int* __restrict__ dsts,
    const float* __restrict__ W,  // [96][32]
    const float* __restrict__ b) {
  __shared__ float vec[2][8][3 * D];
  int t = threadIdx.x, j = t & 31, g = t >> 5;
  float Wc[3 * D];
#pragma unroll
  for (int k = 0; k < 3 * D; k++) Wc[k] = W[k * D + j];
  float B = b[j];
  int it = 0;
  for (int e = blockIdx.x * 8 + g; e < NE; e += gridDim.x * 8, ++it) {
    int s = srcs[e], d = dsts[e];
    float* vv = vec[it & 1][g];
    vv[j] = h_edge[(size_t)e * D + j];
    vv[D + j] = h_node[(size_t)s * D + j];
    vv[2 * D + j] = h_node[(size_t)d * D + j];
    float acc = dot_lds<24>(vv, Wc) + B;
    h_edge[(size_t)e * D + j] = fmaxf(acc, 0.f);
  }
}

// ---------------- final edge layer (out dim 3) + residual ----------------

__global__ __launch_bounds__(256) void k_edge_final(
    const float* __restrict__ h_edge, const float* __restrict__ h_node,
    const int* __restrict__ srcs, const int* __restrict__ dsts,
    const float* __restrict__ W,  // [96][3]
    const float* __restrict__ b,  // [3]
    const float* __restrict__ edge_attr, float* __restrict__ out) {
  int t = threadIdx.x, j = t & 31, g = t >> 5;
  float W0[3], W1[3], W2[3];
#pragma unroll
  for (int c = 0; c < 3; c++) {
    W0[c] = W[(0 * D + j) * 3 + c];
    W1[c] = W[(1 * D + j) * 3 + c];
    W2[c] = W[(2 * D + j) * 3 + c];
  }
  float B0 = b[0], B1 = b[1], B2 = b[2];
  for (int e = blockIdx.x * 8 + g; e < NE; e += gridDim.x * 8) {
    int s = srcs[e], d = dsts[e];
    float he = h_edge[(size_t)e * D + j];
    float hs = h_node[(size_t)s * D + j];
    float hd = h_node[(size_t)d * D + j];
    float a0 = he * W0[0] + hs * W1[0] + hd * W2[0];
    float a1 = he * W0[1] + hs * W1[1] + hd * W2[1];
    float a2 = he * W0[2] + hs * W1[2] + hd * W2[2];
#pragma unroll
    for (int off = 16; off; off >>= 1) {
      a0 += __shfl_xor(a0, off, 32);
      a1 += __shfl_xor(a1, off, 32);
      a2 += __shfl_xor(a2, off, 32);
    }
    if (j == 0) {
      out[(size_t)e * 3 + 0] = edge_attr[(size_t)e * 3 + 0] + a0 + B0;
      out[(size_t)e * 3 + 1] = edge_attr[(size_t)e * 3 + 1] + a1 + B1;
      out[(size_t)e * 3 + 2] = edge_attr[(size_t)e * 3 + 2] + a2 + B2;
    }
  }
}

// ---------------- launch ----------------

extern "C" void kernel_launch(void* const* d_in, const int* in_sizes, int n_in,
                              void* d_out, int out_size, void* d_ws, size_t ws_size,
                              hipStream_t stream) {
  const float* x = (const float*)d_in[0];
  const float* edge_attr = (const float*)d_in[1];
  const int* ei = (const int*)d_in[2];
  const int* src = ei;
  const int* dst = ei + NE;
  const float* w_enc_node_s = (const float*)d_in[3];
  const float* b_enc_node_s = (const float*)d_in[4];
  const float* w_enc_node_h = (const float*)d_in[5];
  const float* b_enc_node_h = (const float*)d_in[6];
  const float* w_enc_node_e = (const float*)d_in[7];
  const float* b_enc_node_e = (const float*)d_in[8];
  const float* w_enc_edge_s = (const float*)d_in[9];
  const float* b_enc_edge_s = (const float*)d_in[10];
  const float* w_enc_edge_h = (const float*)d_in[11];
  const float* b_enc_edge_h = (const float*)d_in[12];
  const float* w_enc_edge_e = (const float*)d_in[13];
  const float* b_enc_edge_e = (const float*)d_in[14];
  const float* w_node_s = (const float*)d_in[15];
  const float* w_node_h = (const float*)d_in[16];
  const float* w_node_e = (const float*)d_in[17];
  const float* w_edge_s = (const float*)d_in[18];
  const float* b_edge_s = (const float*)d_in[19];
  const float* w_edge_h = (const float*)d_in[20];
  const float* b_edge_h = (const float*)d_in[21];
  const float* w_edge_e = (const float*)d_in[22];
  const float* b_edge_e = (const float*)d_in[23];

  char* ws = (char*)d_ws;
  float* h_edge = (float*)ws;  ws += (size_t)NE * D * 4;      // 204.8 MB
  float* h_nodeA = (float*)ws; ws += (size_t)NN * D * 4;      // 12.8 MB
  float* h_nodeB = (float*)ws; ws += (size_t)NN * D * 4;      // 12.8 MB
  int* cnt = (int*)ws;         ws += (size_t)NN * 4;
  float* inv_deg = (float*)ws; ws += (size_t)NN * 4;
  int* rowptr = (int*)ws;      ws += (size_t)(NN + 1) * 4;
  int* fill = (int*)ws;        ws += (size_t)NN * 4;
  int* partial = (int*)ws;     ws += 4096;
  int* eidx = (int*)ws;        ws += (size_t)NE * 4;          // 6.4 MB

  hipMemsetAsync(cnt, 0, (size_t)NN * 4, stream);
  hipMemsetAsync(fill, 0, (size_t)NN * 4, stream);

  k_deg<<<1024, 256, 0, stream>>>(dst, cnt);
  k_invdeg<<<(NN + 255) / 256, 256, 0, stream>>>(cnt, inv_deg);
  int nb = (NN + 1023) / 1024;  // 98
  k_scanA<<<nb, 1024, 0, stream>>>(cnt, rowptr, partial);
  k_scanB<<<1, 1, 0, stream>>>(partial, nb);
  k_scanC<<<nb, 1024, 0, stream>>>(rowptr, partial);
  k_fill<<<1024, 256, 0, stream>>>(dst, rowptr, fill, eidx);

  k_node_enc<<<512, 256, 0, stream>>>(x, w_enc_node_s, b_enc_node_s,
                                      w_enc_node_h, b_enc_node_h,
                                      w_enc_node_e, b_enc_node_e, h_nodeA);
  k_edge_enc<<<2048, 256, 0, stream>>>(edge_attr, w_enc_edge_s, b_enc_edge_s,
                                       w_enc_edge_h, b_enc_edge_h,
                                       w_enc_edge_e, b_enc_edge_e, h_edge);

  // start block
  k_node_proc<<<2048, 256, 0, stream>>>(h_nodeA, h_edge, src, rowptr, eidx, inv_deg,
                                        w_node_s, h_nodeB);
  k_edge_upd<<<2048, 256, 0, stream>>>(h_edge, h_nodeB, src, dst, w_edge_s, b_edge_s);
  // middle blocks (shared weights)
  k_node_proc<<<2048, 256, 0, stream>>>(h_nodeB, h_edge, src, rowptr, eidx, inv_deg,
                                        w_node_h, h_nodeA);
  k_edge_upd<<<2048, 256, 0, stream>>>(h_edge, h_nodeA, src, dst, w_edge_h, b_edge_h);
  k_node_proc<<<2048, 256, 0, stream>>>(h_nodeA, h_edge, src, rowptr, eidx, inv_deg,
                                        w_node_h, h_nodeB);
  k_edge_upd<<<2048, 256, 0, stream>>>(h_edge, h_nodeB, src, dst, w_edge_h, b_edge_h);
  // end block
  k_node_proc<<<2048, 256, 0, stream>>>(h_nodeB, h_edge, src, rowptr, eidx, inv_deg,
                                        w_node_e, h_nodeA);
  k_edge_final<<<2048, 256, 0, stream>>>(h_edge, h_nodeA, src, dst, w_edge_e, b_edge_e,
                                         edge_attr, (float*)d_out);
}

// Round 3
// 1243.535 us; speedup vs baseline: 1.9282x; 1.9282x over previous
//
#include <hip/hip_runtime.h>

#define NN 100000
#define NE 1600000
#define D 32
#define CHUNK 64

// ---------------- bf16 helpers (manual, round-to-nearest-even) ----------------

__device__ inline unsigned short f2b(float f) {
  unsigned int u = __float_as_uint(f);
  u = (u + 0x7FFFu + ((u >> 16) & 1u)) >> 16;
  return (unsigned short)u;
}
__device__ inline float b2f(unsigned short s) {
  return __uint_as_float(((unsigned int)s) << 16);
}

// ============================ CSR build ============================

__global__ void k_deg(const int* __restrict__ dst, int* __restrict__ cnt) {
  int i = blockIdx.x * blockDim.x + threadIdx.x;
  int stride = gridDim.x * blockDim.x;
  for (int e = i; e < NE; e += stride) atomicAdd(&cnt[dst[e]], 1);
}

__global__ void k_invdeg(const int* __restrict__ cnt, float* __restrict__ inv) {
  int v = blockIdx.x * blockDim.x + threadIdx.x;
  if (v < NN) inv[v] = 1.0f / (float)max(cnt[v], 1);
}

__global__ __launch_bounds__(1024) void k_scanA(const int* __restrict__ cnt,
                                                int* __restrict__ rowptr,
                                                int* __restrict__ partial) {
  __shared__ int lds[1024];
  int t = threadIdx.x;
  int i = blockIdx.x * 1024 + t;
  int v = (i < NN) ? cnt[i] : 0;
  lds[t] = v;
  __syncthreads();
  for (int off = 1; off < 1024; off <<= 1) {
    int add = (t >= off) ? lds[t - off] : 0;
    __syncthreads();
    lds[t] += add;
    __syncthreads();
  }
  if (i < NN) rowptr[i] = lds[t] - v;
  if (t == 1023) partial[blockIdx.x] = lds[1023];
}

__global__ void k_scanB(int* __restrict__ partial, int nb) {
  int acc = 0;
  for (int b = 0; b < nb; b++) { int t = partial[b]; partial[b] = acc; acc += t; }
  partial[nb] = acc;
}

__global__ __launch_bounds__(1024) void k_scanC(int* __restrict__ rowptr,
                                                const int* __restrict__ partial) {
  int t = threadIdx.x;
  int i = blockIdx.x * 1024 + t;
  if (i < NN) rowptr[i] += partial[blockIdx.x];
  if (i == 0) rowptr[NN] = NE;
}

__global__ void k_fill(const int* __restrict__ src, const int* __restrict__ dst,
                       const int* __restrict__ rowptr, int* __restrict__ fill,
                       int* __restrict__ eidx, int* __restrict__ src_p,
                       int* __restrict__ dst_p) {
  int i = blockIdx.x * blockDim.x + threadIdx.x;
  int stride = gridDim.x * blockDim.x;
  for (int e = i; e < NE; e += stride) {
    int d = dst[e];
    int slot = atomicAdd(&fill[d], 1);
    int p = rowptr[d] + slot;
    eidx[p] = e;
    src_p[p] = src[e];
    dst_p[p] = d;
  }
}

// ============================ helpers ============================

template <int K4>
__device__ inline float dot_lds(const float* __restrict__ lv, const float* __restrict__ Wc) {
  float acc = 0.f;
  const float4* v4 = (const float4*)lv;
#pragma unroll
  for (int kk = 0; kk < K4; kk++) {
    float4 h = v4[kk];
    acc = fmaf(h.x, Wc[4 * kk + 0], acc);
    acc = fmaf(h.y, Wc[4 * kk + 1], acc);
    acc = fmaf(h.z, Wc[4 * kk + 2], acc);
    acc = fmaf(h.w, Wc[4 * kk + 3], acc);
  }
  return acc;
}

// ============ node encoder + Q0 projection (Q0 = h0 @ Wn[0:32]) ============

__global__ __launch_bounds__(256) void k_node_enc_fin(
    const float* __restrict__ x,
    const float* __restrict__ ws, const float* __restrict__ bs,
    const float* __restrict__ wh, const float* __restrict__ bh,
    const float* __restrict__ we, const float* __restrict__ be,
    const float* __restrict__ Wn,  // w_node_s, rows 0..31
    float2* __restrict__ R2) {
  __shared__ float hrow[8][D];
  int t = threadIdx.x, j = t & 31, g = t >> 5;
  float Ws = ws[j], Bs = bs[j], Bh = bh[j], Be = be[j];
  float Wh[D], We_[D], Wq[D];
#pragma unroll
  for (int k = 0; k < D; k++) {
    Wh[k] = wh[k * D + j];
    We_[k] = we[k * D + j];
    Wq[k] = Wn[k * D + j];
  }
  for (int v = blockIdx.x * 8 + g; v < NN; v += gridDim.x * 8) {
    float h = fmaxf(fmaf(x[v], Ws, Bs), 0.f);
#pragma unroll
    for (int L = 0; L < 2; L++) {
      hrow[g][j] = h;
      h = fmaxf(dot_lds<8>(hrow[g], Wh) + Bh, 0.f);
    }
    hrow[g][j] = h;
    h = fmaxf(dot_lds<8>(hrow[g], We_) + Be, 0.f);
    hrow[g][j] = h;
    float q = dot_lds<8>(hrow[g], Wq);
    R2[(size_t)v * D + j] = make_float2(0.f, q);
  }
}

// ==== node finalize: h = acc/deg; project P2/Q and P3; zero acc ====

__global__ __launch_bounds__(256) void k_fin(
    float* __restrict__ acc, const float* __restrict__ inv_deg,
    const float* __restrict__ We,  // [96][32] NEXT edge layer (rows 32..95 used)
    const float* __restrict__ Wn,  // [64][32] NEXT node msg (rows 0..31 used)
    float2* __restrict__ R2, float* __restrict__ P3out) {
  __shared__ float hrow[8][D];
  int t = threadIdx.x, j = t & 31, g = t >> 5;
  float Wp2[D], Wp3[D], Wq[D];
#pragma unroll
  for (int k = 0; k < D; k++) {
    Wp2[k] = We[(32 + k) * D + j];
    Wp3[k] = We[(64 + k) * D + j];
    Wq[k] = Wn[k * D + j];
  }
  for (int v = blockIdx.x * 8 + g; v < NN; v += gridDim.x * 8) {
    float h = acc[(size_t)v * D + j] * inv_deg[v];
    acc[(size_t)v * D + j] = 0.f;
    hrow[g][j] = h;
    float p2 = dot_lds<8>(hrow[g], Wp2);
    float q = dot_lds<8>(hrow[g], Wq);
    float p3 = dot_lds<8>(hrow[g], Wp3);
    R2[(size_t)v * D + j] = make_float2(p2, q);
    P3out[(size_t)v * D + j] = p3;
  }
}

// ==== final node finalize: P2f/P3f [NN,3] for the 96x3 output layer ====

__global__ __launch_bounds__(256) void k_fin4(
    float* __restrict__ acc, const float* __restrict__ inv_deg,
    const float* __restrict__ We,  // w_edge_e [96][3]
    float* __restrict__ P2f, float* __restrict__ P3f) {
  __shared__ float hrow[8][D];
  int t = threadIdx.x, j = t & 31, g = t >> 5;
  for (int v = blockIdx.x * 8 + g; v < NN; v += gridDim.x * 8) {
    float h = acc[(size_t)v * D + j] * inv_deg[v];
    hrow[g][j] = h;
    if (j < 6) {
      int c = j % 3;
      int off = (j < 3) ? 32 : 64;
      float s = 0.f;
#pragma unroll
      for (int k = 0; k < D; k++) s = fmaf(hrow[g][k], We[(off + k) * 3 + c], s);
      if (j < 3) P2f[(size_t)v * 3 + c] = s;
      else       P3f[(size_t)v * 3 + c] = s;
    }
  }
}

// ==== fused: edge encoder + first message + segmented scatter ====

__global__ __launch_bounds__(256) void k_fe0(
    const float* __restrict__ edge_attr, const int* __restrict__ eidx,
    const float2* __restrict__ R2,  // .y = Q0
    const int* __restrict__ src_p, const int* __restrict__ dst_p,
    float* __restrict__ acc,
    const float* __restrict__ ws, const float* __restrict__ bs,
    const float* __restrict__ wh, const float* __restrict__ bh,
    const float* __restrict__ we, const float* __restrict__ be,
    const float* __restrict__ Wn,  // w_node_s rows 32..63
    unsigned short* __restrict__ h_edge) {
  __shared__ float hrow[8][D];
  int t = threadIdx.x, j = t & 31, g = t >> 5;
  float Ws0 = ws[0 * D + j], Ws1 = ws[1 * D + j], Ws2 = ws[2 * D + j];
  float Bs = bs[j], Bh = bh[j], Be = be[j];
  float Wh[D], We_[D], W2[D];
#pragma unroll
  for (int k = 0; k < D; k++) {
    Wh[k] = wh[k * D + j];
    We_[k] = we[k * D + j];
    W2[k] = Wn[(32 + k) * D + j];
  }
  int p0 = (blockIdx.x * 8 + g) * CHUNK;
  float accv = 0.f;
  int cur = dst_p[p0];
  for (int p = p0; p < p0 + CHUNK; ++p) {
    int s = src_p[p], d = dst_p[p], e = eidx[p];
    float a0 = edge_attr[(size_t)e * 3 + 0];
    float a1 = edge_attr[(size_t)e * 3 + 1];
    float a2 = edge_attr[(size_t)e * 3 + 2];
    float q = R2[(size_t)s * D + j].y;
    float h = fmaf(a0, Ws0, fmaf(a1, Ws1, fmaf(a2, Ws2, Bs)));
    h = fmaxf(h, 0.f);
#pragma unroll
    for (int L = 0; L < 2; L++) {
      hrow[g][j] = h;
      h = fmaxf(dot_lds<8>(hrow[g], Wh) + Bh, 0.f);
    }
    hrow[g][j] = h;
    h = fmaxf(dot_lds<8>(hrow[g], We_) + Be, 0.f);
    h_edge[(size_t)p * D + j] = f2b(h);
    hrow[g][j] = h;
    float m = fmaxf(dot_lds<8>(hrow[g], W2) + q, 0.f);
    if (d != cur) {
      atomicAdd(&acc[(size_t)cur * D + j], accv);
      accv = 0.f;
      cur = d;
    }
    accv += m;
  }
  atomicAdd(&acc[(size_t)cur * D + j], accv);
}

// ==== fused: edge update + next message + segmented scatter ====
// h_new = relu(h_e@We[0:32] + P2[s] + P3[d] + b); msg = relu(h_new@Wn[32:64] + Q[s])

__global__ __launch_bounds__(256) void k_fe(
    unsigned short* __restrict__ h_edge, const float2* __restrict__ R2,
    const float* __restrict__ P3, const int* __restrict__ src_p,
    const int* __restrict__ dst_p, float* __restrict__ acc,
    const float* __restrict__ We, const float* __restrict__ be,
    const float* __restrict__ Wn) {
  __shared__ float tile[8][4][D];
  __shared__ float hrow[8][D];
  int t = threadIdx.x, j = t & 31, g = t >> 5;
  float W1[D], W2[D];
#pragma unroll
  for (int k = 0; k < D; k++) {
    W1[k] = We[k * D + j];
    W2[k] = Wn[(32 + k) * D + j];
  }
  float B = be[j];
  int p0 = (blockIdx.x * 8 + g) * CHUNK;
  float accv = 0.f;
  int cur = dst_p[p0];
  // prefetch first 4 rows (4 rows x 32ch x bf16 = 256B = 32 lanes x uint2)
  uint2 gh = ((const uint2*)(h_edge + (size_t)p0 * D))[j];
  for (int batch = 0; batch < CHUNK / 4; ++batch) {
    int pb = p0 + batch * 4;
    float4 tv;
    tv.x = b2f((unsigned short)(gh.x & 0xFFFFu));
    tv.y = b2f((unsigned short)(gh.x >> 16));
    tv.z = b2f((unsigned short)(gh.y & 0xFFFFu));
    tv.w = b2f((unsigned short)(gh.y >> 16));
    ((float4*)tile[g])[j] = tv;
    int s[4], d[4];
    float2 r[4];
    float p3v[4];
#pragma unroll
    for (int i = 0; i < 4; i++) {
      s[i] = src_p[pb + i];
      d[i] = dst_p[pb + i];
    }
#pragma unroll
    for (int i = 0; i < 4; i++) {
      r[i] = R2[(size_t)s[i] * D + j];
      p3v[i] = P3[(size_t)d[i] * D + j];
    }
    if (batch < CHUNK / 4 - 1)
      gh = ((const uint2*)(h_edge + (size_t)(pb + 4) * D))[j];
#pragma unroll
    for (int i = 0; i < 4; i++) {
      float a = B + r[i].x + p3v[i] + dot_lds<8>(tile[g][i], W1);
      float hn = fmaxf(a, 0.f);
      h_edge[(size_t)(pb + i) * D + j] = f2b(hn);
      hrow[g][j] = hn;
      float m = fmaxf(dot_lds<8>(hrow[g], W2) + r[i].y, 0.f);
      if (d[i] != cur) {
        atomicAdd(&acc[(size_t)cur * D + j], accv);
        accv = 0.f;
        cur = d[i];
      }
      accv += m;
    }
  }
  atomicAdd(&acc[(size_t)cur * D + j], accv);
}

// ==== final edge layer: out[eidx[p]] = ea + h_e@We[0:32] + P2f[s] + P3f[d] + b ====

__global__ __launch_bounds__(256) void k_fe4(
    const unsigned short* __restrict__ h_edge, const float* __restrict__ edge_attr,
    const int* __restrict__ eidx, const int* __restrict__ src_p,
    const int* __restrict__ dst_p, const float* __restrict__ P2f,
    const float* __restrict__ P3f, const float* __restrict__ We,  // [96][3]
    const float* __restrict__ be, float* __restrict__ out) {
  int t = threadIdx.x, j = t & 31, g = t >> 5;
  float Wc0 = We[j * 3 + 0], Wc1 = We[j * 3 + 1], Wc2 = We[j * 3 + 2];
  float B0 = be[0], B1 = be[1], B2 = be[2];
  int ngroups = gridDim.x * 8;
  for (int p = blockIdx.x * 8 + g; p < NE; p += ngroups) {
    float h = b2f(h_edge[(size_t)p * D + j]);
    int s = src_p[p], d = dst_p[p], e = eidx[p];
    float c0 = h * Wc0, c1 = h * Wc1, c2 = h * Wc2;
#pragma unroll
    for (int off = 16; off; off >>= 1) {
      c0 += __shfl_xor(c0, off, 32);
      c1 += __shfl_xor(c1, off, 32);
      c2 += __shfl_xor(c2, off, 32);
    }
    if (j == 0) {
      out[(size_t)e * 3 + 0] = edge_attr[(size_t)e * 3 + 0] + P2f[(size_t)s * 3 + 0] + P3f[(size_t)d * 3 + 0] + B0 + c0;
      out[(size_t)e * 3 + 1] = edge_attr[(size_t)e * 3 + 1] + P2f[(size_t)s * 3 + 1] + P3f[(size_t)d * 3 + 1] + B1 + c1;
      out[(size_t)e * 3 + 2] = edge_attr[(size_t)e * 3 + 2] + P2f[(size_t)s * 3 + 2] + P3f[(size_t)d * 3 + 2] + B2 + c2;
    }
  }
}

// ============================ launch ============================

extern "C" void kernel_launch(void* const* d_in, const int* in_sizes, int n_in,
                              void* d_out, int out_size, void* d_ws, size_t ws_size,
                              hipStream_t stream) {
  const float* x = (const float*)d_in[0];
  const float* edge_attr = (const float*)d_in[1];
  const int* ei = (const int*)d_in[2];
  const int* src = ei;
  const int* dst = ei + NE;
  const float* w_enc_node_s = (const float*)d_in[3];
  const float* b_enc_node_s = (const float*)d_in[4];
  const float* w_enc_node_h = (const float*)d_in[5];
  const float* b_enc_node_h = (const float*)d_in[6];
  const float* w_enc_node_e = (const float*)d_in[7];
  const float* b_enc_node_e = (const float*)d_in[8];
  const float* w_enc_edge_s = (const float*)d_in[9];
  const float* b_enc_edge_s = (const float*)d_in[10];
  const float* w_enc_edge_h = (const float*)d_in[11];
  const float* b_enc_edge_h = (const float*)d_in[12];
  const float* w_enc_edge_e = (const float*)d_in[13];
  const float* b_enc_edge_e = (const float*)d_in[14];
  const float* w_node_s = (const float*)d_in[15];
  const float* w_node_h = (const float*)d_in[16];
  const float* w_node_e = (const float*)d_in[17];
  const float* w_edge_s = (const float*)d_in[18];
  const float* b_edge_s = (const float*)d_in[19];
  const float* w_edge_h = (const float*)d_in[20];
  const float* b_edge_h = (const float*)d_in[21];
  const float* w_edge_e = (const float*)d_in[22];
  const float* b_edge_e = (const float*)d_in[23];

  // workspace layout (~174 MB total; round-1's 238 MB was proven safe)
  char* w = (char*)d_ws;
  unsigned short* h_edge = (unsigned short*)w; w += (size_t)NE * D * 2;  // 102.4 MB
  int* eidx = (int*)w;        w += (size_t)NE * 4;            // 6.4 MB
  int* src_p = (int*)w;       w += (size_t)NE * 4;            // 6.4 MB
  int* dst_p = (int*)w;       w += (size_t)NE * 4;            // 6.4 MB
  float* acc = (float*)w;     w += (size_t)NN * D * 4;        // 12.8 MB
  float2* R2 = (float2*)w;    w += (size_t)NN * D * 8;        // 25.6 MB
  float* P3 = (float*)w;      w += (size_t)NN * D * 4;        // 12.8 MB (aliased by P2f/P3f later)
  float* P2f = P3;
  float* P3f = P3 + (size_t)NN * 3;
  int* cnt = (int*)w;         w += (size_t)NN * 4;
  float* inv_deg = (float*)w; w += (size_t)NN * 4;
  int* rowptr = (int*)w;      w += (size_t)(NN + 1) * 4;
  int* fill = (int*)w;        w += (size_t)NN * 4;
  int* partial = (int*)w;     w += 4096;

  hipMemsetAsync(cnt, 0, (size_t)NN * 4, stream);
  hipMemsetAsync(fill, 0, (size_t)NN * 4, stream);
  hipMemsetAsync(acc, 0, (size_t)NN * D * 4, stream);

  k_deg<<<1024, 256, 0, stream>>>(dst, cnt);
  k_invdeg<<<(NN + 255) / 256, 256, 0, stream>>>(cnt, inv_deg);
  int nb = (NN + 1023) / 1024;
  k_scanA<<<nb, 1024, 0, stream>>>(cnt, rowptr, partial);
  k_scanB<<<1, 1, 0, stream>>>(partial, nb);
  k_scanC<<<nb, 1024, 0, stream>>>(rowptr, partial);
  k_fill<<<1024, 256, 0, stream>>>(src, dst, rowptr, fill, eidx, src_p, dst_p);

  // node encoder -> Q0 (into R2.y)
  k_node_enc_fin<<<1024, 256, 0, stream>>>(x, w_enc_node_s, b_enc_node_s,
                                           w_enc_node_h, b_enc_node_h,
                                           w_enc_node_e, b_enc_node_e,
                                           w_node_s, R2);

  int feb = NE / CHUNK / 8;  // 3125 blocks

  // edge encoder + msg(A_s) -> acc
  k_fe0<<<feb, 256, 0, stream>>>(edge_attr, eidx, R2, src_p, dst_p, acc,
                                 w_enc_edge_s, b_enc_edge_s,
                                 w_enc_edge_h, b_enc_edge_h,
                                 w_enc_edge_e, b_enc_edge_e,
                                 w_node_s, h_edge);
  // h1 projections for B_s (w_edge_s) and msg A_h1 (w_node_h)
  k_fin<<<1024, 256, 0, stream>>>(acc, inv_deg, w_edge_s, w_node_h, R2, P3);
  // B_s + msg(A_h1)
  k_fe<<<feb, 256, 0, stream>>>(h_edge, R2, P3, src_p, dst_p, acc,
                                w_edge_s, b_edge_s, w_node_h);
  // h2 projections for B_h1 (w_edge_h) and msg A_h2 (w_node_h)
  k_fin<<<1024, 256, 0, stream>>>(acc, inv_deg, w_edge_h, w_node_h, R2, P3);
  // B_h1 + msg(A_h2)
  k_fe<<<feb, 256, 0, stream>>>(h_edge, R2, P3, src_p, dst_p, acc,
                                w_edge_h, b_edge_h, w_node_h);
  // h3 projections for B_h2 (w_edge_h) and msg A_e (w_node_e)
  k_fin<<<1024, 256, 0, stream>>>(acc, inv_deg, w_edge_h, w_node_e, R2, P3);
  // B_h2 + msg(A_e)
  k_fe<<<feb, 256, 0, stream>>>(h_edge, R2, P3, src_p, dst_p, acc,
                                w_edge_h, b_edge_h, w_node_e);
  // h4 -> P2f/P3f for final 96x3 layer
  k_fin4<<<1024, 256, 0, stream>>>(acc, inv_deg, w_edge_e, P2f, P3f);
  // final edge layer + residual, scatter to original order
  k_fe4<<<2048, 256, 0, stream>>>(h_edge, edge_attr, eidx, src_p, dst_p,
                                  P2f, P3f, w_edge_e, b_edge_e, (float*)d_out);
}